// Round 1
// baseline (21.127 us; speedup 1.0000x reference)
//
#include <hip/hip_runtime.h>

#define BATCH   2
#define K       256
#define NEDGE   257
#define NPTS    76800          // 240*320
#define PCHUNK  512
#define CB      (NPTS / PCHUNK)   // 150 chunks per batch
#define NBLOCKS (BATCH * CB)      // 300
#define THREADS 256

// ws layout:
//   uint  minSlots[BATCH*K]      (512 entries)  — per-center global min, float bits
//   float partials[NBLOCKS]      (300 entries)  — per-block dist2 partial sums

__global__ void chamfer_init(unsigned int* __restrict__ minSlots,
                             float* __restrict__ partials) {
    int t = threadIdx.x;
    for (int i = t; i < BATCH * K; i += THREADS) minSlots[i] = 0x7F800000u; // +inf
    for (int i = t; i < NBLOCKS; i += THREADS)   partials[i] = 0.0f;
}

__global__ __launch_bounds__(THREADS)
void chamfer_main(const float* __restrict__ target,
                  const float* __restrict__ edges,
                  unsigned int* __restrict__ minSlots,
                  float* __restrict__ partials) {
    __shared__ float sC[K];        // centers for this batch
    __shared__ float sP[PCHUNK];   // staged point chunk
    __shared__ float sRed[THREADS];

    const int t     = threadIdx.x;
    const int b     = blockIdx.x / CB;
    const int chunk = blockIdx.x % CB;

    // centers from edges (K == THREADS)
    {
        const float* e = edges + b * NEDGE;
        sC[t] = 0.5f * (e[t] + e[t + 1]);
    }
    // stage points (coalesced)
    {
        const float* tp = target + (size_t)b * NPTS + (size_t)chunk * PCHUNK;
        sP[t]           = tp[t];
        sP[t + THREADS] = tp[t + THREADS];
    }
    __syncthreads();

    // ---- Pass 1: per-point min over centers (dist2 contribution) ----
    const float d0 = sP[t];
    const float d1 = sP[t + THREADS];
    float m0 = 1e30f, m1 = 1e30f;
    const float4* c4 = (const float4*)sC;
    #pragma unroll 8
    for (int i = 0; i < K / 4; ++i) {
        const float4 c = c4[i];
        float x;
        x = d0 - c.x; m0 = fminf(m0, x * x);
        x = d1 - c.x; m1 = fminf(m1, x * x);
        x = d0 - c.y; m0 = fminf(m0, x * x);
        x = d1 - c.y; m1 = fminf(m1, x * x);
        x = d0 - c.z; m0 = fminf(m0, x * x);
        x = d1 - c.z; m1 = fminf(m1, x * x);
        x = d0 - c.w; m0 = fminf(m0, x * x);
        x = d1 - c.w; m1 = fminf(m1, x * x);
    }
    float localSum = m0 + m1;

    // ---- Pass 2: per-center min over staged points (dist1 contribution) ----
    const float c = sC[t];
    float rm = 1e30f;
    const float4* p4 = (const float4*)sP;
    #pragma unroll 8
    for (int i = 0; i < PCHUNK / 4; ++i) {
        const float4 p = p4[i];
        float x;
        x = c - p.x; rm = fminf(rm, x * x);
        x = c - p.y; rm = fminf(rm, x * x);
        x = c - p.z; rm = fminf(rm, x * x);
        x = c - p.w; rm = fminf(rm, x * x);
    }
    // non-negative floats: uint bit compare == float compare; min is order-independent
    atomicMin(&minSlots[b * K + t], __float_as_uint(rm));

    // ---- deterministic block reduction of dist2 partial ----
    sRed[t] = localSum;
    __syncthreads();
    for (int s = THREADS / 2; s > 0; s >>= 1) {
        if (t < s) sRed[t] += sRed[t + s];
        __syncthreads();
    }
    if (t == 0) partials[blockIdx.x] = sRed[0];
}

__global__ void chamfer_final(const unsigned int* __restrict__ minSlots,
                              const float* __restrict__ partials,
                              float* __restrict__ out) {
    __shared__ float sRed[THREADS];
    const int t = threadIdx.x;
    // dist1: sum the 512 per-center mins (thread t takes slots t and t+256)
    float s = __uint_as_float(minSlots[t]) + __uint_as_float(minSlots[t + THREADS]);
    // dist2: sum the 300 per-block partials in a fixed assignment
    for (int i = t; i < NBLOCKS; i += THREADS) s += partials[i];
    sRed[t] = s;
    __syncthreads();
    for (int st = THREADS / 2; st > 0; st >>= 1) {
        if (t < st) sRed[t] += sRed[t + st];
        __syncthreads();
    }
    if (t == 0) out[0] = sRed[0] * (1.0f / BATCH);
}

extern "C" void kernel_launch(void* const* d_in, const int* in_sizes, int n_in,
                              void* d_out, int out_size, void* d_ws, size_t ws_size,
                              hipStream_t stream) {
    const float* target = (const float*)d_in[0];   // [2,1,240,320] fp32
    const float* edges  = (const float*)d_in[1];   // [2,257] fp32
    float* out = (float*)d_out;

    unsigned int* minSlots = (unsigned int*)d_ws;
    float* partials = (float*)(minSlots + BATCH * K);

    chamfer_init<<<1, THREADS, 0, stream>>>(minSlots, partials);
    chamfer_main<<<NBLOCKS, THREADS, 0, stream>>>(target, edges, minSlots, partials);
    chamfer_final<<<1, THREADS, 0, stream>>>(minSlots, partials, out);
}